// Round 8
// baseline (68.797 us; speedup 1.0000x reference)
//
#include <hip/hip_runtime.h>

#define NEGINF -1000000000.0f

typedef __attribute__((ext_vector_type(4))) float f32x4;
typedef __attribute__((ext_vector_type(2))) float f32x2;
typedef _Float16 half8 __attribute__((ext_vector_type(8)));
typedef _Float16 half4 __attribute__((ext_vector_type(4)));

constexpr int Bn = 64, Cn = 1024, Qn = 128, Dn = 128;

// ---------------- k0: bake query into wave-coalesced MFMA frag layouts ----------------
// qA[b][kk*8+mt][lane][j]  = fp16 query[b][mt*16+(lane&15)][kk*32+(lane>>4)*8+j]
// qB[b][kk2*8+ntD][lane][j] = fp16 query[b][qmap(kk2*32+(lane>>4)*8+j)][ntD*16+(lane&15)]
//   qmap(i) = (i&~31) | (((i>>2)&1)<<4) | (((i>>3)&3)<<2) | (i&3)   (mm2 k-bijection)
// qts_g[b][q] = q_term + (1-mask)*NEGINF
__global__ __launch_bounds__(256) void k0_kernel(
    const float* __restrict__ qry, const float* __restrict__ W,
    const float* __restrict__ mask,
    _Float16* __restrict__ qA, _Float16* __restrict__ qB, float* __restrict__ qts_g)
{
    __shared__ float wq[128];
    __shared__ _Float16 qs[128][136];
    const int b = blockIdx.x, t = threadIdx.x;
    if (t < 128) wq[t] = W[128 + t];
    __syncthreads();

    {   // pass 1: fp16 convert into LDS + qterm
        int q = t >> 1, h = t & 1;
        const float* qr = qry + ((size_t)b * Qn + q) * Dn + h * 64;
        float acc = 0.f;
        for (int j = 0; j < 64; j += 4) {
            f32x4 v = *(const f32x4*)(qr + j);
            int d = h * 64 + j;
            acc += v.x * wq[d] + v.y * wq[d + 1] + v.z * wq[d + 2] + v.w * wq[d + 3];
            half4 hv;
            hv[0] = (_Float16)v.x; hv[1] = (_Float16)v.y;
            hv[2] = (_Float16)v.z; hv[3] = (_Float16)v.w;
            *(half4*)&qs[q][d] = hv;
        }
        acc += __shfl_xor(acc, 1);
        if (h == 0) qts_g[b * Qn + q] = acc + (1.0f - mask[b * Qn + q]) * NEGINF;
    }
    __syncthreads();

    {   // pass 2a: qA
        int fm = t >> 3;          // kk*8+mt
        int l0 = (t & 7) * 8;
        int kk = fm >> 3, mt = fm & 7;
        _Float16* dst = qA + ((size_t)b * 32 + fm) * 512;
#pragma unroll
        for (int l = l0; l < l0 + 8; ++l) {
            int q = mt * 16 + (l & 15), d = kk * 32 + (l >> 4) * 8;
            *(half8*)&dst[l * 8] = *(const half8*)&qs[q][d];
        }
    }
    {   // pass 2b: qB
        int fm = t >> 3;          // kk2*8+ntD
        int l0 = (t & 7) * 8;
        int kk2 = fm >> 3, ntD = fm & 7;
        _Float16* dst = qB + ((size_t)b * 32 + fm) * 512;
#pragma unroll
        for (int l = l0; l < l0 + 8; ++l) {
            int d = ntD * 16 + (l & 15);
            half8 w;
#pragma unroll
            for (int j = 0; j < 8; ++j) {
                int i = kk2 * 32 + (l >> 4) * 8 + j;
                int q = (i & ~31) | (((i >> 2) & 1) << 4) | (((i >> 3) & 3) << 2) | (i & 3);
                w[j] = qs[q][d];
            }
            *(half8*)&dst[l * 8] = w;
        }
    }
}

// ---------------- k1: barrier-free waves; 16 c-rows per wave ----------------
// grid (16, Bn) x 256 threads (4 waves). Writes cols 0,1,2; per-block q2c partial.
__global__ __launch_bounds__(256, 4) void k1_kernel(
    const float* __restrict__ ctx, const _Float16* __restrict__ qA,
    const _Float16* __restrict__ qB, const float* __restrict__ qts_g,
    const float* __restrict__ W,
    float* __restrict__ out, float* __restrict__ ws_part, float* __restrict__ ws_ms)
{
    __shared__ float wfull[256];       // w_c | w_s
    __shared__ float qts[128];
    __shared__ float mw_s[4], sw_s[4];
    __shared__ float partf[4][128];

    const int b = blockIdx.y, cg = blockIdx.x;
    const int t = threadIdx.x;
    const int wave = t >> 6, lane = t & 63, g = lane >> 4, l15 = lane & 15;
    const int c0 = cg * 64 + wave * 16;          // wave's first ctx row (local tile base)
    const float* ctxB = ctx + (size_t)b * Cn * Dn;

    if (t < 128) wfull[t] = W[t];
    else if (t < 256) wfull[t] = W[256 + t - 128];
    if (t < 128) qts[t] = qts_g[b * Qn + t];
    __syncthreads();

    const _Float16* qAb = qA + (size_t)b * 32 * 512;
    const _Float16* qBb = qB + (size_t)b * 32 * 512;

    // ---- mm1: S^T[q][c] (fp16) with fused c_term
    f32x4 acc1[8] = {};
    float cterm = 0.f;
#pragma unroll
    for (int kk = 0; kk < 4; ++kk) {
        const int dbase = kk * 32 + g * 8;
        const float* pc = ctxB + (size_t)(c0 + l15) * Dn + dbase;
        f32x4 v0 = *(const f32x4*)pc, v1 = *(const f32x4*)(pc + 4);
        f32x4 s0 = *(const f32x4*)&wfull[128 + dbase], s1 = *(const f32x4*)&wfull[128 + dbase + 4];
        f32x4 c0w = *(const f32x4*)&wfull[dbase], c1w = *(const f32x4*)&wfull[dbase + 4];
        cterm += v0.x * c0w.x + v0.y * c0w.y + v0.z * c0w.z + v0.w * c0w.w
               + v1.x * c1w.x + v1.y * c1w.y + v1.z * c1w.z + v1.w * c1w.w;
        half8 ah;
        ah[0] = (_Float16)(v0.x * s0.x); ah[1] = (_Float16)(v0.y * s0.y);
        ah[2] = (_Float16)(v0.z * s0.z); ah[3] = (_Float16)(v0.w * s0.w);
        ah[4] = (_Float16)(v1.x * s1.x); ah[5] = (_Float16)(v1.y * s1.y);
        ah[6] = (_Float16)(v1.z * s1.z); ah[7] = (_Float16)(v1.w * s1.w);
#pragma unroll
        for (int mt = 0; mt < 8; ++mt) {
            half8 qf = *(const half8*)&qAb[(size_t)(kk * 8 + mt) * 512 + lane * 8];
            acc1[mt] = __builtin_amdgcn_mfma_f32_16x16x32_f16(qf, ah, acc1[mt], 0, 0, 0);
        }
    }
    cterm += __shfl_xor(cterm, 16);
    cterm += __shfl_xor(cterm, 32);   // all lanes: c_term for row c0+l15

    // ---- softmax over q per column
#pragma unroll
    for (int mt = 0; mt < 8; ++mt)
#pragma unroll
        for (int r = 0; r < 4; ++r) acc1[mt][r] += qts[mt * 16 + g * 4 + r];

    float mx = -3.4e38f;
#pragma unroll
    for (int mt = 0; mt < 8; ++mt)
#pragma unroll
        for (int r = 0; r < 4; ++r) mx = fmaxf(mx, acc1[mt][r]);
    mx = fmaxf(mx, __shfl_xor(mx, 16));
    mx = fmaxf(mx, __shfl_xor(mx, 32));
    float sum = 0.f;
#pragma unroll
    for (int mt = 0; mt < 8; ++mt)
#pragma unroll
        for (int r = 0; r < 4; ++r) {
            float pv = __expf(acc1[mt][r] - mx);
            acc1[mt][r] = pv;
            sum += pv;
        }
    sum += __shfl_xor(sum, 16);
    sum += __shfl_xor(sum, 32);

    // pack P^T into A-frags (k-bijection matches qB); inv colsums
    half8 pa[4];
#pragma unroll
    for (int kk2 = 0; kk2 < 4; ++kk2)
#pragma unroll
        for (int j = 0; j < 8; ++j)
            pa[kk2][j] = (_Float16)acc1[2 * kk2 + (j >> 2)][j & 3];

    float inv[4];
#pragma unroll
    for (int r = 0; r < 4; ++r) inv[r] = 1.0f / __shfl(sum, g * 4 + r);

    // ---- per-wave online-softmax stats over its 16 columns (in-register)
    float mcol = mx + cterm;                 // column c0+l15's m (same across g)
    float Mw = mcol;
#pragma unroll
    for (int off = 1; off < 16; off <<= 1) Mw = fmaxf(Mw, __shfl_xor(Mw, off));
    float ecol = __expf(mcol - Mw);
    float Sw = ecol;
#pragma unroll
    for (int off = 1; off < 16; off <<= 1) Sw += __shfl_xor(Sw, off);

    // ---- q2c partial over the wave's 16 rows + col 0 store (coalesced, early stores)
    f32x2 part = {};
    const int dl = lane * 2;
#pragma unroll
    for (int i = 0; i < 16; ++i) {
        int c = c0 + i;
        f32x2 cv = *(const f32x2*)(ctxB + (size_t)c * Dn + dl);
        float e = __shfl(ecol, i);
        part.x += e * cv.x; part.y += e * cv.y;
        *(f32x2*)(out + ((size_t)(b * Cn + c)) * 512 + dl) = cv;   // col 0
    }

    // ---- mm2: c2q[c][d] = sum_q P[c][q] query[q][d]
    f32x4 acc2[8] = {};
#pragma unroll
    for (int kk2 = 0; kk2 < 4; ++kk2)
#pragma unroll
        for (int ntD = 0; ntD < 8; ++ntD) {
            half8 qb = *(const half8*)&qBb[(size_t)(kk2 * 8 + ntD) * 512 + lane * 8];
            acc2[ntD] = __builtin_amdgcn_mfma_f32_16x16x32_f16(pa[kk2], qb, acc2[ntD], 0, 0, 0);
        }

    // ---- direct frag-pattern stores: cols 1 (c2q), 2 (ctx*c2q); 64B segments
#pragma unroll
    for (int r = 0; r < 4; ++r) {
        int c = c0 + g * 4 + r;
        float is = inv[r];
        const float* crow = ctxB + (size_t)c * Dn;
        float* orow = out + ((size_t)(b * Cn + c)) * 512;
#pragma unroll
        for (int ntD = 0; ntD < 8; ++ntD) {
            int d = ntD * 16 + l15;
            float c2 = acc2[ntD][r] * is;
            orow[128 + d] = c2;
            orow[256 + d] = crow[d] * c2;
        }
    }

    // ---- block combine of 4 wave-partials -> ws (one barrier)
    *(f32x2*)&partf[wave][dl] = part;
    if (lane == 0) { mw_s[wave] = Mw; sw_s[wave] = Sw; }
    __syncthreads();
    if (t < 128) {
        float M = fmaxf(fmaxf(mw_s[0], mw_s[1]), fmaxf(mw_s[2], mw_s[3]));
        float p = 0.f, S = 0.f;
#pragma unroll
        for (int w = 0; w < 4; ++w) {
            float e = __expf(mw_s[w] - M);
            p += e * partf[w][t];
            S += e * sw_s[w];
        }
        ws_part[((size_t)(b * 16 + cg)) * 128 + t] = p;
        if (t == 0) {
            ws_ms[(b * 16 + cg) * 2 + 0] = M;
            ws_ms[(b * 16 + cg) * 2 + 1] = S;
        }
    }
}

// ---- k3: combine 16 chunk-partials -> q2c; write col 3 (ctx*q2c)
__global__ __launch_bounds__(256) void k3_kernel(
    const float* __restrict__ ctx, const float* __restrict__ ws_part,
    const float* __restrict__ ws_ms, float* __restrict__ out)
{
    __shared__ float q2cs[128];
    const int ct = blockIdx.x, b = blockIdx.y, t = threadIdx.x;
    if (t < 128) {
        const float* ms = ws_ms + b * 32;
        float Mg = -3.4e38f;
#pragma unroll
        for (int i = 0; i < 16; ++i) Mg = fmaxf(Mg, ms[2 * i]);
        float num = 0.f, den = 0.f;
#pragma unroll
        for (int i = 0; i < 16; ++i) {
            float e = __expf(ms[2 * i] - Mg);
            num += e * ws_part[((size_t)(b * 16 + i)) * 128 + t];
            den += e * ms[2 * i + 1];
        }
        q2cs[t] = num / den;
    }
    __syncthreads();
    const float* cb = ctx + ((size_t)b * Cn + ct * 128) * Dn;
    float* ob = out + ((size_t)(b * Cn) + ct * 128) * 512;
    for (int step = 0; step < 16; ++step) {
        int c = (t >> 5) + step * 8, d4 = (t & 31) * 4;
        f32x4 v = *(const f32x4*)(cb + (size_t)c * Dn + d4);
        f32x4 q = *(const f32x4*)&q2cs[d4];
        f32x4 w;
        w.x = v.x * q.x; w.y = v.y * q.y; w.z = v.z * q.z; w.w = v.w * q.w;
        *(f32x4*)(ob + (size_t)c * 512 + 384 + d4) = w;
    }
}

extern "C" void kernel_launch(void* const* d_in, const int* in_sizes, int n_in,
                              void* d_out, int out_size, void* d_ws, size_t ws_size,
                              hipStream_t stream) {
    const float* ctx  = (const float*)d_in[0];
    const float* qry  = (const float*)d_in[1];
    const float* W    = (const float*)d_in[2];
    const float* mask = (const float*)d_in[3];
    float* out = (float*)d_out;

    float* ws_part = (float*)d_ws;                          // 64*16*128 f32 = 512 KB
    float* ws_ms   = ws_part + (size_t)Bn * 16 * 128;       // 64*16*2 f32 = 8 KB
    float* qts_g   = ws_ms + (size_t)Bn * 32;               // 64*128 f32 = 32 KB
    _Float16* qA   = (_Float16*)(qts_g + (size_t)Bn * Qn);  // 64*32*512 fp16 = 2 MB
    _Float16* qB   = qA + (size_t)Bn * 32 * 512;            // 2 MB

    k0_kernel<<<dim3(Bn), 256, 0, stream>>>(qry, W, mask, qA, qB, qts_g);
    k1_kernel<<<dim3(16, Bn), 256, 0, stream>>>(ctx, qA, qB, qts_g, W, out, ws_part, ws_ms);
    k3_kernel<<<dim3(8, Bn), 256, 0, stream>>>(ctx, ws_part, ws_ms, out);
}

// Round 10
// 55.052 us; speedup vs baseline: 1.2497x; 1.2497x over previous
//
#include <hip/hip_runtime.h>

#define NEGINF -1000000000.0f
#define L2E 1.44269504088896340736f

typedef __attribute__((ext_vector_type(4))) float f32x4;
typedef _Float16 half8 __attribute__((ext_vector_type(8)));
typedef _Float16 half4 __attribute__((ext_vector_type(4)));

__device__ inline float exp2fast(float x) { return __builtin_amdgcn_exp2f(x); }

constexpr int Bn = 64, Cn = 1024, Qn = 128, Dn = 128;
constexpr int QSTR = 136;   // LDS halves stride; 272 B rows -> 2-way (free) b128 bank pattern
constexpr int CSTR = 132;   // LDS float stride for cq bounce

// ---------------- k0: per-batch query precompute ----------------
// qh   [b][q][d] fp16 row-major
// qT2p [b][d][i] fp16, i = p(q) bijection BAKED (k1 reads linearly)
// qts_g[b][q] = (q_term + (1-mask)*NEGINF) * log2(e)
__global__ __launch_bounds__(512) void k0_kernel(
    const float* __restrict__ qry, const float* __restrict__ W,
    const float* __restrict__ mask,
    _Float16* __restrict__ qh, _Float16* __restrict__ qT2p, float* __restrict__ qts_g)
{
    __shared__ float wq[128];
    __shared__ _Float16 qs[128][132];
    const int b = blockIdx.x, t = threadIdx.x;
    if (t < 128) wq[t] = W[128 + t];
    __syncthreads();

    {   // pass 1: fp16 convert + qh + LDS stage + qterm
        int q = t >> 2, h = t & 3;
        const float* qr = qry + ((size_t)b * Qn + q) * Dn + h * 32;
        float acc = 0.f;
        for (int j = 0; j < 32; j += 4) {
            f32x4 v = *(const f32x4*)(qr + j);
            int d = h * 32 + j;
            acc += v.x * wq[d] + v.y * wq[d + 1] + v.z * wq[d + 2] + v.w * wq[d + 3];
            half4 hv;
            hv[0] = (_Float16)v.x; hv[1] = (_Float16)v.y;
            hv[2] = (_Float16)v.z; hv[3] = (_Float16)v.w;
            *(half4*)&qh[((size_t)b * Qn + q) * Dn + d] = hv;
            *(half4*)&qs[q][d] = hv;
        }
        acc += __shfl_xor(acc, 1);
        acc += __shfl_xor(acc, 2);
        if (h == 0) qts_g[b * Qn + q] = (acc + (1.0f - mask[b * Qn + q]) * NEGINF) * L2E;
    }
    __syncthreads();
    {   // pass 2: baked-transpose write, linear in i
        int d = t >> 2, h = t & 3;
#pragma unroll
        for (int blk = 0; blk < 4; ++blk) {
            int i0 = h * 32 + blk * 8;
            half8 w;
#pragma unroll
            for (int j = 0; j < 8; ++j) {
                int i = i0 + j;
                int q = (i & ~31) | (((i >> 2) & 1) << 4) | (((i >> 3) & 3) << 2) | (i & 3);
                w[j] = qs[q][d];
            }
            *(half8*)&qT2p[((size_t)b * Dn + d) * Qn + i0] = w;
        }
    }
}

// ---------------- k1: S^T, softmax, c2q; q2c partials; cols 0,1,2 at the tail ----------------
// LDS map (bytes), total 72256 -> 2 blocks/CU:
//   0      qrow [128][136] fp16 (34816) + qT2 [128][136] fp16 (34816) = 69632
//          } partf [16][128] f32 = 8192 overlays qT2 (after mm2)
//          } cq [128][132] f32 = 67584 overlays all (after partf consumed)
//   69632  wfull 256 f (w_c | w_s, both * L2E)
//   70656  qts  128 f
//   71168  mloc 128 f
//   71680  wv   128 f
//   72192  red  16 f
__global__ __launch_bounds__(512, 4) void k1_kernel(
    const float* __restrict__ ctx, const _Float16* __restrict__ qh,
    const _Float16* __restrict__ qT2p, const float* __restrict__ qts_g,
    const float* __restrict__ W,
    float* __restrict__ out, float* __restrict__ ws_part, float* __restrict__ ws_ms)
{
    __shared__ char smem[72256];
    _Float16* qrow = (_Float16*)smem;
    _Float16* rows = (_Float16*)smem;
    float* wfull = (float*)(smem + 69632);
    float* qts   = (float*)(smem + 70656);
    float* mloc  = (float*)(smem + 71168);
    float* wv    = (float*)(smem + 71680);
    float* red   = (float*)(smem + 72192);
    _Float16* qT2 = (_Float16*)(smem + 34816);
    float* partf = (float*)(smem + 34816);   // after mm2
    float* cq    = (float*)smem;             // after partf consumed

    const int b = blockIdx.y, cg = blockIdx.x, c0 = cg * 128;
    const int t = threadIdx.x;
    const float* ctxB = ctx + (size_t)b * Cn * Dn;

    // ---- phase 1: coalesced copies qh->qrow, qT2p->qT2; + wfull (scaled), qts
    {
        int r = t >> 1, h = t & 1;
        const _Float16* src = (r < 128)
            ? qh   + ((size_t)b * Qn + r) * Dn + h * 64
            : qT2p + ((size_t)b * Dn + (r - 128)) * Qn + h * 64;
        _Float16* dst = rows + r * QSTR + h * 64;
#pragma unroll
        for (int s = 0; s < 8; ++s)
            *(half8*)(dst + s * 8) = *(const half8*)(src + s * 8);
    }
    if (t < 128) wfull[t] = W[t] * L2E;
    else if (t < 256) wfull[t] = W[256 + (t - 128)] * L2E;
    if (t < 128) qts[t] = qts_g[b * Qn + t];
    __syncthreads();

    const int wave = t >> 6, lane = t & 63, g = lane >> 4, l15 = lane & 15;
    const int cw = wave * 16;
    const int cl = cw + l15;

    // ---- phase 2: mm1  S'^T[q][c] (log2-scaled, fp16) with fused c_term
    f32x4 acc1[8] = {};
    float cterm = 0.f;
#pragma unroll
    for (int kk = 0; kk < 4; ++kk) {
        const int dbase = kk * 32 + g * 8;
        const float* pc = ctxB + (size_t)(c0 + cl) * Dn + dbase;
        f32x4 v0 = *(const f32x4*)pc, v1 = *(const f32x4*)(pc + 4);
        f32x4 s0 = *(const f32x4*)&wfull[128 + dbase], s1 = *(const f32x4*)&wfull[128 + dbase + 4];
        f32x4 c0w = *(const f32x4*)&wfull[dbase], c1w = *(const f32x4*)&wfull[dbase + 4];
        cterm += v0.x * c0w.x + v0.y * c0w.y + v0.z * c0w.z + v0.w * c0w.w
               + v1.x * c1w.x + v1.y * c1w.y + v1.z * c1w.z + v1.w * c1w.w;
        half8 ah;
        ah[0] = (_Float16)(v0.x * s0.x); ah[1] = (_Float16)(v0.y * s0.y);
        ah[2] = (_Float16)(v0.z * s0.z); ah[3] = (_Float16)(v0.w * s0.w);
        ah[4] = (_Float16)(v1.x * s1.x); ah[5] = (_Float16)(v1.y * s1.y);
        ah[6] = (_Float16)(v1.z * s1.z); ah[7] = (_Float16)(v1.w * s1.w);
#pragma unroll
        for (int mt = 0; mt < 8; ++mt) {
            half8 qf = *(const half8*)&qrow[(mt * 16 + l15) * QSTR + dbase];
            acc1[mt] = __builtin_amdgcn_mfma_f32_16x16x32_f16(qf, ah, acc1[mt], 0, 0, 0);
        }
    }
    cterm += __shfl_xor(cterm, 16);
    cterm += __shfl_xor(cterm, 32);

    // ---- phase 3: +q_term(+mask); softmax (base-2) over q per column
#pragma unroll
    for (int mt = 0; mt < 8; ++mt)
#pragma unroll
        for (int r = 0; r < 4; ++r) acc1[mt][r] += qts[mt * 16 + g * 4 + r];

    float mx = -3.4e38f;
#pragma unroll
    for (int mt = 0; mt < 8; ++mt)
#pragma unroll
        for (int r = 0; r < 4; ++r) mx = fmaxf(mx, acc1[mt][r]);
    mx = fmaxf(mx, __shfl_xor(mx, 16));
    mx = fmaxf(mx, __shfl_xor(mx, 32));
    float sum = 0.f;
#pragma unroll
    for (int mt = 0; mt < 8; ++mt)
#pragma unroll
        for (int r = 0; r < 4; ++r) {
            float pv = exp2fast(acc1[mt][r] - mx);
            acc1[mt][r] = pv;
            sum += pv;
        }
    sum += __shfl_xor(sum, 16);
    sum += __shfl_xor(sum, 32);
    if (g == 0) mloc[cl] = mx + cterm;

    half8 pa[4];
#pragma unroll
    for (int kk2 = 0; kk2 < 4; ++kk2)
#pragma unroll
        for (int j = 0; j < 8; ++j)
            pa[kk2][j] = (_Float16)acc1[2 * kk2 + (j >> 2)][j & 3];

    float inv[4];
#pragma unroll
    for (int r = 0; r < 4; ++r) inv[r] = 1.0f / __shfl(sum, g * 4 + r);

    // ---- mm2: c2q[c][d] = sum_q P[c][q] query[q][d]
    f32x4 acc2[8] = {};
#pragma unroll
    for (int kk2 = 0; kk2 < 4; ++kk2)
#pragma unroll
        for (int ntD = 0; ntD < 8; ++ntD) {
            half8 qb = *(const half8*)&qT2[(ntD * 16 + l15) * QSTR + kk2 * 32 + 8 * g];
            acc2[ntD] = __builtin_amdgcn_mfma_f32_16x16x32_f16(pa[kk2], qb, acc2[ntD], 0, 0, 0);
        }
    __syncthreads();   // qrow/qT2 reads done; mloc complete

    // ---- phase 4a: Mloc, wv, Sloc (shuffle reductions)
    float vm = mloc[t & 127];
    float m = vm;
#pragma unroll
    for (int off = 1; off < 64; off <<= 1) m = fmaxf(m, __shfl_xor(m, off));
    if (lane == 0) red[wave] = m;
    __syncthreads();
    float Mloc = red[0];
#pragma unroll
    for (int i = 1; i < 8; ++i) Mloc = fmaxf(Mloc, red[i]);
    float e = exp2fast(vm - Mloc);
    if (t < 128) wv[t] = e;
    float s = e;
#pragma unroll
    for (int off = 1; off < 64; off <<= 1) s += __shfl_xor(s, off);
    if (lane == 0) red[8 + wave] = s;
    __syncthreads();
    float Sloc = red[8] + red[9];

    // ---- phase 4b: partial q2c -> ws (partf overlays qT2; ctx rows L1/L2-hot)
    const int grp = t >> 5, d4 = (t & 31) * 4;
    {
        const float* cb = ctxB + (size_t)(c0 + grp * 8) * Dn;
        f32x4 a = {};
#pragma unroll
        for (int i = 0; i < 8; ++i) {
            f32x4 cv = *(const f32x4*)(cb + (size_t)i * Dn + d4);
            float w = wv[grp * 8 + i];
            a.x += w * cv.x; a.y += w * cv.y; a.z += w * cv.z; a.w += w * cv.w;
        }
        *(f32x4*)&partf[grp * 128 + d4] = a;
    }
    __syncthreads();
    if (t < 128) {
        float s2 = 0.f;
#pragma unroll
        for (int g2 = 0; g2 < 16; ++g2) s2 += partf[g2 * 128 + t];
        ws_part[((size_t)(b * 8 + cg)) * 128 + t] = s2;
    }
    if (t == 0) {
        ws_ms[(b * 8 + cg) * 2 + 0] = Mloc;
        ws_ms[(b * 8 + cg) * 2 + 1] = Sloc;
    }
    __syncthreads();   // partf consumed -> cq may overlay

    // ---- phase 5: stage c2q into LDS
#pragma unroll
    for (int r = 0; r < 4; ++r) {
        int c = cw + g * 4 + r;
        float is = inv[r];
#pragma unroll
        for (int ntD = 0; ntD < 8; ++ntD)
            cq[c * CSTR + ntD * 16 + l15] = acc2[ntD][r] * is;
    }
    __syncthreads();

    // ---- phase 6 (TAIL, no barrier after): coalesced store of cols 0,1,2
#pragma unroll
    for (int step = 0; step < 8; ++step) {
        int c = grp + step * 16;
        f32x4 q = *(const f32x4*)&cq[c * CSTR + d4];
        f32x4 cv = *(const f32x4*)(ctxB + (size_t)(c0 + c) * Dn + d4);
        float* orow = out + ((size_t)(b * Cn + c0 + c)) * 512;
        *(f32x4*)(orow + d4) = cv;
        *(f32x4*)(orow + 128 + d4) = q;
        f32x4 pr;
        pr.x = cv.x * q.x; pr.y = cv.y * q.y; pr.z = cv.z * q.z; pr.w = cv.w * q.w;
        *(f32x4*)(orow + 256 + d4) = pr;
    }
}

// ---- k3: combine chunk-partials -> q2c; write col 3 (ctx*q2c)
__global__ __launch_bounds__(256) void k3_kernel(
    const float* __restrict__ ctx, const float* __restrict__ ws_part,
    const float* __restrict__ ws_ms, float* __restrict__ out)
{
    __shared__ float q2cs[128];
    const int ct = blockIdx.x, b = blockIdx.y, t = threadIdx.x;
    if (t < 128) {
        const float* ms = ws_ms + b * 16;
        float Mg = -3.4e38f;
#pragma unroll
        for (int i = 0; i < 8; ++i) Mg = fmaxf(Mg, ms[2 * i]);
        float num = 0.f, den = 0.f;
#pragma unroll
        for (int i = 0; i < 8; ++i) {
            float e = exp2fast(ms[2 * i] - Mg);
            num += e * ws_part[((size_t)(b * 8 + i)) * 128 + t];
            den += e * ms[2 * i + 1];
        }
        q2cs[t] = num / den;
    }
    __syncthreads();
    const float* cb = ctx + ((size_t)b * Cn + ct * 128) * Dn;
    float* ob = out + ((size_t)(b * Cn) + ct * 128) * 512;
    for (int step = 0; step < 16; ++step) {
        int c = (t >> 5) + step * 8, d4 = (t & 31) * 4;
        f32x4 v = *(const f32x4*)(cb + (size_t)c * Dn + d4);
        f32x4 q = *(const f32x4*)&q2cs[d4];
        f32x4 w;
        w.x = v.x * q.x; w.y = v.y * q.y; w.z = v.z * q.z; w.w = v.w * q.w;
        *(f32x4*)(ob + (size_t)c * 512 + 384 + d4) = w;
    }
}

extern "C" void kernel_launch(void* const* d_in, const int* in_sizes, int n_in,
                              void* d_out, int out_size, void* d_ws, size_t ws_size,
                              hipStream_t stream) {
    const float* ctx  = (const float*)d_in[0];
    const float* qry  = (const float*)d_in[1];
    const float* W    = (const float*)d_in[2];
    const float* mask = (const float*)d_in[3];
    float* out = (float*)d_out;

    float* ws_part  = (float*)d_ws;                         // 64*8*128 f32
    float* ws_ms    = ws_part + (size_t)Bn * 8 * 128;       // 64*16 f32
    float* qts_g    = ws_ms + (size_t)Bn * 16;              // 64*128 f32
    _Float16* qh    = (_Float16*)(qts_g + (size_t)Bn * Qn); // 2 MB
    _Float16* qT2p  = qh + (size_t)Bn * Qn * Dn;            // 2 MB

    k0_kernel<<<dim3(Bn), 512, 0, stream>>>(qry, W, mask, qh, qT2p, qts_g);
    k1_kernel<<<dim3(8, Bn), 512, 0, stream>>>(ctx, qh, qT2p, qts_g, W, out, ws_part, ws_ms);
    k3_kernel<<<dim3(8, Bn), 256, 0, stream>>>(ctx, ws_part, ws_ms, out);
}

// Round 11
// 48.697 us; speedup vs baseline: 1.4127x; 1.1305x over previous
//
#include <hip/hip_runtime.h>

#define NEGINF -1000000000.0f
#define L2E 1.44269504088896340736f

typedef __attribute__((ext_vector_type(4))) float f32x4;
typedef _Float16 half8 __attribute__((ext_vector_type(8)));
typedef _Float16 half4 __attribute__((ext_vector_type(4)));

__device__ inline float exp2fast(float x) { return __builtin_amdgcn_exp2f(x); }

constexpr int Bn = 64, Cn = 1024, Qn = 128, Dn = 128;
constexpr int QSTR = 136;   // halves; 272 B rows -> 2-way (free) b128 bank pattern
constexpr int CSTR = 132;   // floats; 528 B rows for cq bounce

// LDS map (bytes), total 72768 -> 2 blocks/CU:
//   0      qrow [128][136] fp16 = 34816  } overlaid (after mm2) by cq [128][132] f32 = 67584
//   34816  qT2  [128][136] fp16 = 34816  }   ... then partf [16][128] f32 = 8192 (after stores)
//   69632  wfull 384 f (1536)  — all * log2(e)
//   71168  qts  128 f          — log2-scaled
//   71680  mloc 128 f
//   72192  wv   128 f
//   72704  red  16 f (64)

__global__ __launch_bounds__(512, 4) void k1_kernel(
    const float* __restrict__ ctx, const float* __restrict__ qry,
    const float* __restrict__ W, const float* __restrict__ mask,
    float* __restrict__ out, float* __restrict__ ws_part, float* __restrict__ ws_ms)
{
    __shared__ char smem[72768];
    _Float16* qrow = (_Float16*)smem;
    _Float16* qT2  = (_Float16*)(smem + 34816);
    float* wfull = (float*)(smem + 69632);
    float* qts   = (float*)(smem + 71168);
    float* mloc  = (float*)(smem + 71680);
    float* wv    = (float*)(smem + 72192);
    float* red   = (float*)(smem + 72704);
    float* cq    = (float*)smem;            // after mm2
    float* partf = (float*)(smem + 34816);  // after stores (cq reads barriered first)

    // XCD grouping: grid (Bn, 8); flat wgid = b + 64*cg -> xcd = b%8 for all 8
    // tiles of batch b => the batch's query slab is fetched into ONE XCD L2.
    const int b = blockIdx.x, cg = blockIdx.y, c0 = cg * 128;
    const int t = threadIdx.x;
    const float* ctxB = ctx + (size_t)b * Cn * Dn;
    const float* qryB = qry + (size_t)b * Qn * Dn;

    if (t < 384) wfull[t] = W[t] * L2E;
    __syncthreads();

    // ---- phase 1: stage query fp16 (row-major + bijection-transposed); qterm(+mask)
    {
        int q = t >> 2, h = t & 3;
        const float* qr = qryB + q * Dn + h * 32;
        int p = ((q >> 5) << 5) + 8 * ((q >> 2) & 3) + (q & 3) + 4 * ((q >> 4) & 1);
        float acc = 0.f;
        for (int j = 0; j < 32; j += 4) {
            f32x4 v = *(const f32x4*)(qr + j);
            int d = h * 32 + j;
            acc += v.x * wfull[128 + d] + v.y * wfull[128 + d + 1]
                 + v.z * wfull[128 + d + 2] + v.w * wfull[128 + d + 3];
            half4 hv;
            hv[0] = (_Float16)v.x; hv[1] = (_Float16)v.y;
            hv[2] = (_Float16)v.z; hv[3] = (_Float16)v.w;
            *(half4*)&qrow[q * QSTR + d] = hv;
            qT2[(d + 0) * QSTR + p] = hv[0];
            qT2[(d + 1) * QSTR + p] = hv[1];
            qT2[(d + 2) * QSTR + p] = hv[2];
            qT2[(d + 3) * QSTR + p] = hv[3];
        }
        acc += __shfl_xor(acc, 1);
        acc += __shfl_xor(acc, 2);
        if (h == 0) qts[q] = acc + (1.0f - mask[b * Qn + q]) * (NEGINF * L2E);
    }
    __syncthreads();

    const int wave = t >> 6, lane = t & 63, g = lane >> 4, l15 = lane & 15;
    const int cw = wave * 16;
    const int cl = cw + l15;   // this lane's ctx row within the 128-tile

    // ---- phase 2: mm1  S'^T[q][c] (log2-scaled fp16) with fused c_term
    f32x4 acc1[8] = {};
    float cterm = 0.f;
#pragma unroll
    for (int kk = 0; kk < 4; ++kk) {
        const int dbase = kk * 32 + g * 8;
        const float* pc = ctxB + (size_t)(c0 + cl) * Dn + dbase;
        f32x4 v0 = *(const f32x4*)pc, v1 = *(const f32x4*)(pc + 4);
        f32x4 s0 = *(const f32x4*)&wfull[256 + dbase], s1 = *(const f32x4*)&wfull[256 + dbase + 4];
        f32x4 c0w = *(const f32x4*)&wfull[dbase], c1w = *(const f32x4*)&wfull[dbase + 4];
        cterm += v0.x * c0w.x + v0.y * c0w.y + v0.z * c0w.z + v0.w * c0w.w
               + v1.x * c1w.x + v1.y * c1w.y + v1.z * c1w.z + v1.w * c1w.w;
        half8 ah;
        ah[0] = (_Float16)(v0.x * s0.x); ah[1] = (_Float16)(v0.y * s0.y);
        ah[2] = (_Float16)(v0.z * s0.z); ah[3] = (_Float16)(v0.w * s0.w);
        ah[4] = (_Float16)(v1.x * s1.x); ah[5] = (_Float16)(v1.y * s1.y);
        ah[6] = (_Float16)(v1.z * s1.z); ah[7] = (_Float16)(v1.w * s1.w);
#pragma unroll
        for (int mt = 0; mt < 8; ++mt) {
            half8 qf = *(const half8*)&qrow[(mt * 16 + l15) * QSTR + dbase];
            acc1[mt] = __builtin_amdgcn_mfma_f32_16x16x32_f16(qf, ah, acc1[mt], 0, 0, 0);
        }
    }
    cterm += __shfl_xor(cterm, 16);
    cterm += __shfl_xor(cterm, 32);   // all lanes: c_term for row cl (log2-scaled)

    // ---- phase 3: +q_term(+mask); softmax (base-2) over q per column
#pragma unroll
    for (int mt = 0; mt < 8; ++mt)
#pragma unroll
        for (int r = 0; r < 4; ++r) acc1[mt][r] += qts[mt * 16 + g * 4 + r];

    float mx = -3.4e38f;
#pragma unroll
    for (int mt = 0; mt < 8; ++mt)
#pragma unroll
        for (int r = 0; r < 4; ++r) mx = fmaxf(mx, acc1[mt][r]);
    mx = fmaxf(mx, __shfl_xor(mx, 16));
    mx = fmaxf(mx, __shfl_xor(mx, 32));
    float sum = 0.f;
#pragma unroll
    for (int mt = 0; mt < 8; ++mt)
#pragma unroll
        for (int r = 0; r < 4; ++r) {
            float pv = exp2fast(acc1[mt][r] - mx);
            acc1[mt][r] = pv;
            sum += pv;
        }
    sum += __shfl_xor(sum, 16);
    sum += __shfl_xor(sum, 32);
    if (g == 0) mloc[cl] = mx + cterm;

    // pack P^T into A-frags (bijection k = 4g+(j&3)+16(j>>2)); inv colsums
    half8 pa[4];
#pragma unroll
    for (int kk2 = 0; kk2 < 4; ++kk2)
#pragma unroll
        for (int j = 0; j < 8; ++j)
            pa[kk2][j] = (_Float16)acc1[2 * kk2 + (j >> 2)][j & 3];

    float inv[4];
#pragma unroll
    for (int r = 0; r < 4; ++r) inv[r] = 1.0f / __shfl(sum, g * 4 + r);

    // ---- mm2: c2q[c][d] = sum_q P[c][q] query[q][d]
    f32x4 acc2[8] = {};
#pragma unroll
    for (int kk2 = 0; kk2 < 4; ++kk2)
#pragma unroll
        for (int ntD = 0; ntD < 8; ++ntD) {
            half8 qb = *(const half8*)&qT2[(ntD * 16 + l15) * QSTR + kk2 * 32 + 8 * g];
            acc2[ntD] = __builtin_amdgcn_mfma_f32_16x16x32_f16(pa[kk2], qb, acc2[ntD], 0, 0, 0);
        }
    __syncthreads();   // qrow/qT2 reads done; mloc complete

    // ---- phase 5: stage c2q into LDS (overlays qrow/qT2)
#pragma unroll
    for (int r = 0; r < 4; ++r) {
        int c = cw + g * 4 + r;
        float is = inv[r];
#pragma unroll
        for (int ntD = 0; ntD < 8; ++ntD)
            cq[c * CSTR + ntD * 16 + l15] = acc2[ntD][r] * is;
    }
    __syncthreads();

    // ---- phase 6: coalesced store of cols 0 (ctx), 1 (c2q), 2 (ctx*c2q)
    const int grp = t >> 5, d4 = (t & 31) * 4;
#pragma unroll
    for (int step = 0; step < 8; ++step) {
        int c = grp + step * 16;
        f32x4 q = *(const f32x4*)&cq[c * CSTR + d4];
        f32x4 cv = *(const f32x4*)(ctxB + (size_t)(c0 + c) * Dn + d4);
        float* orow = out + ((size_t)(b * Cn + c0 + c)) * 512;
        *(f32x4*)(orow + d4) = cv;
        *(f32x4*)(orow + 128 + d4) = q;
        f32x4 pr;
        pr.x = cv.x * q.x; pr.y = cv.y * q.y; pr.z = cv.z * q.z; pr.w = cv.w * q.w;
        *(f32x4*)(orow + 256 + d4) = pr;
    }

    // ---- phase 4a: Mloc, wv, Sloc  (first sync doubles as phase-6 cq-read completion)
    float vm = mloc[t & 127];
    float m = vm;
#pragma unroll
    for (int off = 1; off < 64; off <<= 1) m = fmaxf(m, __shfl_xor(m, off));
    if (lane == 0) red[wave] = m;
    __syncthreads();
    float Mloc = red[0];
#pragma unroll
    for (int i = 1; i < 8; ++i) Mloc = fmaxf(Mloc, red[i]);
    float e = exp2fast(vm - Mloc);
    if (t < 128) wv[t] = e;
    float s = e;
#pragma unroll
    for (int off = 1; off < 64; off <<= 1) s += __shfl_xor(s, off);
    if (lane == 0) red[8 + wave] = s;
    __syncthreads();
    float Sloc = red[8] + red[9];   // waves 0,1 cover t=0..127

    // ---- phase 4b: partial q2c -> ws (partf overlays cq region; barrier passed)
    {
        const float* cb = ctxB + (size_t)(c0 + grp * 8) * Dn;
        f32x4 a = {};
#pragma unroll
        for (int i = 0; i < 8; ++i) {
            f32x4 cv = *(const f32x4*)(cb + (size_t)i * Dn + d4);
            float w = wv[grp * 8 + i];
            a.x += w * cv.x; a.y += w * cv.y; a.z += w * cv.z; a.w += w * cv.w;
        }
        *(f32x4*)&partf[grp * 128 + d4] = a;
    }
    __syncthreads();
    if (t < 128) {
        float s2 = 0.f;
#pragma unroll
        for (int g2 = 0; g2 < 16; ++g2) s2 += partf[g2 * 128 + t];
        ws_part[((size_t)(b * 8 + cg)) * 128 + t] = s2;
    }
    if (t == 0) {
        ws_ms[(b * 8 + cg) * 2 + 0] = Mloc;
        ws_ms[(b * 8 + cg) * 2 + 1] = Sloc;
    }
}

// ---- k3: combine chunk-partials -> q2c; write col 3 (ctx*q2c) only
__global__ __launch_bounds__(256) void k3_kernel(
    const float* __restrict__ ctx, const float* __restrict__ ws_part,
    const float* __restrict__ ws_ms, float* __restrict__ out)
{
    __shared__ float q2cs[128];
    const int ct = blockIdx.x, b = blockIdx.y, t = threadIdx.x;
    if (t < 128) {
        const float* ms = ws_ms + b * 16;
        float Mg = -3.4e38f;
#pragma unroll
        for (int i = 0; i < 8; ++i) Mg = fmaxf(Mg, ms[2 * i]);
        float num = 0.f, den = 0.f;
#pragma unroll
        for (int i = 0; i < 8; ++i) {
            float e = exp2fast(ms[2 * i] - Mg);
            num += e * ws_part[((size_t)(b * 8 + i)) * 128 + t];
            den += e * ms[2 * i + 1];
        }
        q2cs[t] = num / den;
    }
    __syncthreads();
    const float* cb = ctx + ((size_t)b * Cn + ct * 128) * Dn;
    float* ob = out + ((size_t)(b * Cn) + ct * 128) * 512;
    for (int step = 0; step < 16; ++step) {
        int c = (t >> 5) + step * 8, d4 = (t & 31) * 4;
        f32x4 v = *(const f32x4*)(cb + (size_t)c * Dn + d4);
        f32x4 q = *(const f32x4*)&q2cs[d4];
        f32x4 w;
        w.x = v.x * q.x; w.y = v.y * q.y; w.z = v.z * q.z; w.w = v.w * q.w;
        *(f32x4*)(ob + (size_t)c * 512 + 384 + d4) = w;
    }
}

extern "C" void kernel_launch(void* const* d_in, const int* in_sizes, int n_in,
                              void* d_out, int out_size, void* d_ws, size_t ws_size,
                              hipStream_t stream) {
    const float* ctx  = (const float*)d_in[0];
    const float* qry  = (const float*)d_in[1];
    const float* W    = (const float*)d_in[2];
    const float* mask = (const float*)d_in[3];
    float* out = (float*)d_out;

    float* ws_part = (float*)d_ws;                    // 64*8*128 f32
    float* ws_ms   = ws_part + (size_t)Bn * 8 * 128;  // 64*8*2 f32

    k1_kernel<<<dim3(Bn, 8), 512, 0, stream>>>(ctx, qry, W, mask, out, ws_part, ws_ms);
    k3_kernel<<<dim3(8, Bn), 256, 0, stream>>>(ctx, ws_part, ws_ms, out);
}